// Round 5
// baseline (88.708 us; speedup 1.0000x reference)
//
#include <hip/hip_runtime.h>
#include <hip/hip_fp16.h>
#include <math.h>

#define LRES 2048
#define NB 8
#define KSEL 64
#define EMBD 16
#define NBIN 128
#define BINSCALE 1.28f          // bin = trunc(d2 * 1.28), d2 < 100 -> bin < 128
#define BINW 0.78125f           // 100/128, upper edge = (T+1)*BINW
#define NSLOT 16                // per-lane slot cap (Poisson(1) tail: P(>16) ~ 1e-14)

// packed-f16 dot product with f32 accumulate: d = a.x*b.x + a.y*b.y + c
static __device__ __forceinline__ float fdot2u(unsigned a, unsigned b, float c) {
#if __has_builtin(__builtin_amdgcn_fdot2)
    typedef _Float16 h2f __attribute__((ext_vector_type(2)));
    union { unsigned u; h2f h; } ua, ub;
    ua.u = a; ub.u = b;
    return __builtin_amdgcn_fdot2(ua.h, ub.h, c, false);
#else
    float d;
    asm("v_dot2_f32_f16 %0, %1, %2, %3" : "=v"(d) : "v"(a), "v"(b), "v"(c));
    return d;
#endif
}

// packed half2 add on raw bits
static __device__ __forceinline__ unsigned hadd2u(unsigned a, unsigned b) {
    __half2 ha = *(__half2*)&a, hb = *(__half2*)&b;
    __half2 r = __hadd2(ha, hb);
    return *(unsigned*)&r;
}

// prep: per-residue rho + pack (x,y,z,rho) as half4 into ws
__global__ void prep_kernel(const float* __restrict__ R,
                            const int* __restrict__ seq,
                            const float* __restrict__ emb,
                            const float* __restrict__ w,
                            const float* __restrict__ bias,
                            uint2* __restrict__ pts) {
    int idx = blockIdx.x * blockDim.x + threadIdx.x;
    if (idx < NB * LRES) {
        int s = seq[idx];
        float x = bias[0];
#pragma unroll
        for (int d = 0; d < EMBD; ++d) x += emb[s * EMBD + d] * w[d];
        float rho = 1.6f + 1.2f / (1.0f + expf(-x));
        __half2 h0 = __floats2half2_rn(R[idx * 3 + 0], R[idx * 3 + 1]);
        __half2 h1 = __floats2half2_rn(R[idx * 3 + 2], rho);
        pts[idx] = make_uint2(*(unsigned*)&h0, *(unsigned*)&h1);
    }
}

#define LDS_FENCE() asm volatile("s_waitcnt lgkmcnt(0)" ::: "memory")

// one WAVE per row; 4 independent waves per block.
// pass-1 distance math in packed-f16 via v_dot2_f32_f16: 5 VALU/point, no cvts.
__global__ __launch_bounds__(256, 8) void repel_kernel(const uint2* __restrict__ pts,
                                                       float* __restrict__ partial) {
    const int w    = threadIdx.x >> 6;
    const int lane = threadIdx.x & 63;
    const int row  = blockIdx.x * 4 + w;
    const int b    = row >> 11;
    const int i    = row & (LRES - 1);

    __shared__ unsigned hist[4][NBIN];            // 2 KB
    __shared__ unsigned slots[4][NSLOT][64];      // 16 KB; bank = lane&31: 2-way (free)
    __shared__ unsigned shT[4];
    __shared__ float    shS[4];

    const uint2* __restrict__ P  = pts + (b << 11);
    const uint4* __restrict__ P4 = (const uint4*)P;

    // zero own wave's histogram (2 bins/lane) + default T = NBIN-1 (select all in-cutoff)
    *(uint2*)&hist[w][lane << 1] = make_uint2(0u, 0u);
    if (lane == 0) shT[w] = NBIN - 1;

    // center: negated half2 (x,y) and masked+negated half2 (z, 0); rho_i as f32
    const uint2 ci = P[i];
    const unsigned ncxy = ci.x ^ 0x80008000u;                 // (-cx, -cy) packed
    const unsigned nczv = (ci.y & 0x0000FFFFu) ^ 0x00008000u; // (-cz, +0) packed
    const float rho_i = __high2float(*(__half2*)&ci.y);

    // scalar exclusion window: i is wave-uniform -> SGPR; t covers 128 j's
    const int s_i = __builtin_amdgcn_readfirstlane(i);
    const int tlo = ((s_i - 2 > 0) ? (s_i - 2) : 0) >> 7;
    const int thi = ((s_i + 2 < LRES - 1) ? (s_i + 2) : (LRES - 1)) >> 7;

    const unsigned lane2 = (unsigned)lane << 1;
    const unsigned exbits = __float_as_uint(1.0e9f);          // > any threshold (uint-monotone)
    LDS_FENCE();   // zero-init complete before atomics

    // ---- pass 1: distances (lane owns 32 j's) + fused per-wave histogram ----
    unsigned d2u[32];
#pragma unroll
    for (int t = 0; t < 16; ++t) {
        uint4 u = P4[(t << 6) + lane];               // points j0 (u.x,u.y), j0+1 (u.z,u.w)
        int j0 = (t << 7) + (int)lane2;
        // point A: dxy packed, dz packed with rho slot zeroed
        unsigned dxyA = hadd2u(u.x, ncxy);
        unsigned dzA  = hadd2u(u.y, nczv) & 0x0000FFFFu;      // (dz, 0)
        float d2a = fdot2u(dxyA, dxyA, fdot2u(dzA, dzA, 0.0f));
        // point B
        unsigned dxyB = hadd2u(u.z, ncxy);
        unsigned dzB  = hadd2u(u.w, nczv) & 0x0000FFFFu;
        float d2b = fdot2u(dxyB, dxyB, fdot2u(dzB, dzB, 0.0f));
        unsigned dua = __float_as_uint(d2a);
        unsigned dub = __float_as_uint(d2b);
        if (t == tlo || t == thi) {                  // scalar compare: uniform branch
            int e0 = j0 - i;     e0 = (e0 < 0) ? -e0 : e0;
            int e1 = j0 + 1 - i; e1 = (e1 < 0) ? -e1 : e1;
            if (e0 <= 2) dua = exbits;
            if (e1 <= 2) dub = exbits;
        }
        d2u[2 * t]     = dua;
        d2u[2 * t + 1] = dub;
        if (dua <= 0x42C7FFFFu)                      // d2 < 100.0
            atomicAdd(&hist[w][(unsigned)(d2a * BINSCALE)], 1u);
        if (dub <= 0x42C7FFFFu)
            atomicAdd(&hist[w][(unsigned)(d2b * BINSCALE)], 1u);
    }
    LDS_FENCE();

    // ---- scan: lane holds 2 bins; 64-lane inclusive scan; crossing lane sets T ----
    uint2 hv = *(const uint2*)&hist[w][lane << 1];
    unsigned p = hv.x + hv.y;
    unsigned s = p;
#pragma unroll
    for (int o = 1; o < 64; o <<= 1) {
        unsigned uu = __shfl_up(s, o, 64);
        if (lane >= o) s += uu;
    }
    unsigned e0s = s - p;
    if (s >= KSEL && e0s < KSEL) {                   // unique crossing lane (if total >= 64)
        unsigned sub = (e0s + hv.x >= KSEL) ? 0u : 1u;
        shT[w] = (lane << 1) + sub;                  // whole boundary bin selected
    }
    LDS_FENCE();
    const unsigned T   = shT[w];                     // wave-uniform broadcast read
    const unsigned tkb = __float_as_uint((float)(T + 1) * BINW);

    // ---- capture: branchless; garbage writes at slot[cnt] are overwritten or unread ----
    unsigned cnt = 0;
#pragma unroll
    for (int m = 0; m < 32; ++m) {
        const unsigned jm  = (unsigned)(((m >> 1) << 7) | (m & 1));   // const per m
        unsigned val  = (d2u[m] & 0xFFFFF800u) | jm | lane2;          // j bits disjoint
        unsigned sel  = (d2u[m] < tkb) ? 1u : 0u;
        unsigned widx = (cnt > NSLOT - 1) ? (NSLOT - 1) : cnt;
        slots[w][widx][lane] = val;
        cnt += sel;
    }
    LDS_FENCE();

    // ---- eval own slots (wave runs max-cnt ~4 iterations) + wave reduce ----
    float acc = 0.0f;
    for (unsigned k = 0; k < cnt; ++k) {
        unsigned key = slots[w][k][lane];
        unsigned j = key & 2047u;
        float d2 = __uint_as_float(key & 0xFFFFF800u);
        float r = __fsqrt_rn(fmaxf(d2, 1e-12f));
        uint2 pj = P[j];
        float rho_j = __high2float(*(__half2*)&pj.y);
        float x = (rho_i + rho_j - r) * (1.0f / 0.3f);
        float sp = fmaxf(x, 0.0f) + __logf(1.0f + __expf(-fabsf(x)));
        float t = fminf(fmaxf((r - 8.0f) * 0.5f, 0.0f), 1.0f);
        float sw = 1.0f - t * t * (3.0f - 2.0f * t);
        acc += 10.0f * sp * sw;
    }
#pragma unroll
    for (int o = 32; o > 0; o >>= 1) acc += __shfl_down(acc, o, 64);

    // ---- block combine -> ONE plain store per block ----
    if (lane == 0) shS[w] = acc;
    __syncthreads();
    if (threadIdx.x == 0)
        partial[blockIdx.x] = shS[0] + shS[1] + shS[2] + shS[3];
}

// out[b] = sum of 512 per-block partials (blocks 512b .. 512b+511)
__global__ void reduce_kernel(const float* __restrict__ partial, float* __restrict__ out) {
    __shared__ float sh[4];
    const int b = blockIdx.x;
    const int tid = threadIdx.x;
    float acc = partial[(b << 9) + tid] + partial[(b << 9) + 256 + tid];
#pragma unroll
    for (int o = 32; o > 0; o >>= 1) acc += __shfl_down(acc, o, 64);
    if ((tid & 63) == 0) sh[tid >> 6] = acc;
    __syncthreads();
    if (tid == 0) out[b] = sh[0] + sh[1] + sh[2] + sh[3];
}

extern "C" void kernel_launch(void* const* d_in, const int* in_sizes, int n_in,
                              void* d_out, int out_size, void* d_ws, size_t ws_size,
                              hipStream_t stream) {
    const float* R    = (const float*)d_in[0];   // (8, 2048, 3) f32
    const int*   seq  = (const int*)d_in[1];     // (8, 2048) int
    const float* emb  = (const float*)d_in[2];   // (20, 16) f32
    const float* w    = (const float*)d_in[3];   // (1, 16) f32
    const float* bias = (const float*)d_in[4];   // (1,) f32
    float* out = (float*)d_out;                  // (8,) f32

    uint2* pts     = (uint2*)d_ws;                                       // 128 KB
    float* partial = (float*)((char*)d_ws + NB * LRES * sizeof(uint2));  // 16 KB

    prep_kernel<<<(NB * LRES + 255) / 256, 256, 0, stream>>>(R, seq, emb, w, bias, pts);
    repel_kernel<<<NB * LRES / 4, 256, 0, stream>>>(pts, partial);
    reduce_kernel<<<NB, 256, 0, stream>>>(partial, out);
}

// Round 6
// 84.713 us; speedup vs baseline: 1.0472x; 1.0472x over previous
//
#include <hip/hip_runtime.h>
#include <hip/hip_fp16.h>
#include <math.h>

#define LRES 2048
#define NB 8
#define KSEL 64
#define EMBD 16
#define NAA 20
#define NBIN 128
#define BINSCALE 1.28f          // bin = trunc(d2 * 1.28), d2 < 100 -> bin < 128
#define BINW 0.78125f           // 100/128, upper edge = (T+1)*BINW
#define NSLOT 16                // per-lane slot cap (Poisson(1) tail: P(>16) ~ 1e-14)

// packed-f16 dot product with f32 accumulate: d = a.x*b.x + a.y*b.y + c
static __device__ __forceinline__ float fdot2u(unsigned a, unsigned b, float c) {
#if __has_builtin(__builtin_amdgcn_fdot2)
    typedef _Float16 h2f __attribute__((ext_vector_type(2)));
    union { unsigned u; h2f h; } ua, ub;
    ua.u = a; ub.u = b;
    return __builtin_amdgcn_fdot2(ua.h, ub.h, c, false);
#else
    float d;
    asm("v_dot2_f32_f16 %0, %1, %2, %3" : "=v"(d) : "v"(a), "v"(b), "v"(c));
    return d;
#endif
}

static __device__ __forceinline__ unsigned hadd2u(unsigned a, unsigned b) {
    __half2 ha = *(__half2*)&a, hb = *(__half2*)&b;
    __half2 r = __hadd2(ha, hb);
    return *(unsigned*)&r;
}

#define LDS_FENCE() asm volatile("s_waitcnt lgkmcnt(0)" ::: "memory")

// ONE fused kernel: 512 threads = 8 waves = 8 rows per block; 256 blocks/batch.
// Block stages its batch's 2048 points (half4: x,y,z,rho) into LDS once
// (rho via 20-entry AA table — the size head only depends on amino-acid id),
// then each wave runs the histogram-select-eval pipeline entirely out of LDS.
__global__ __launch_bounds__(512, 8) void repel_kernel(
    const float* __restrict__ R,
    const int* __restrict__ seq,
    const float* __restrict__ emb,
    const float* __restrict__ wv,
    const float* __restrict__ bias,
    float* __restrict__ partial)
{
    const int tid  = threadIdx.x;
    const int w    = tid >> 6;
    const int lane = tid & 63;
    const int row  = blockIdx.x * 8 + w;
    const int b    = row >> 11;
    const int i    = row & (LRES - 1);

    __shared__ uint2          Pl[LRES];             // 16 KB packed points
    __shared__ unsigned       hist[8][NBIN];        // 4 KB
    __shared__ unsigned short slots[8][NSLOT][64];  // 16 KB (j only)
    __shared__ float          rho_tab[NAA];         // 80 B
    __shared__ unsigned       shT[8];
    __shared__ float          shS[8];

    const float* __restrict__ Rb = R + b * (LRES * 3);
    const int*   __restrict__ Sb = seq + b * LRES;

    // ---- stage 0: rho table (20 dots of length 16) ----
    if (tid < NAA) {
        float x = bias[0];
#pragma unroll
        for (int d = 0; d < EMBD; ++d) x += emb[tid * EMBD + d] * wv[d];
        rho_tab[tid] = 1.6f + 1.2f / (1.0f + __expf(-x));
    }
    // zero own wave's histogram (2 bins/lane) + default T = NBIN-1
    *(uint2*)&hist[w][lane << 1] = make_uint2(0u, 0u);
    if (lane == 0) shT[w] = NBIN - 1;
    __syncthreads();

    // ---- stage 1: pack 4 points/thread into LDS (lane-stride-8B writes: free) ----
#pragma unroll
    for (int k = 0; k < 4; ++k) {
        int p = (k << 9) + tid;
        float x = Rb[p * 3 + 0], y = Rb[p * 3 + 1], z = Rb[p * 3 + 2];
        float rho = rho_tab[Sb[p]];
        __half2 h0 = __floats2half2_rn(x, y);
        __half2 h1 = __floats2half2_rn(z, rho);
        Pl[p] = make_uint2(*(unsigned*)&h0, *(unsigned*)&h1);
    }
    __syncthreads();

    // center: negated half2 (x,y) and masked+negated half2 (z, 0); rho_i as f32
    const uint2 ci = Pl[i];
    const unsigned ncxy = ci.x ^ 0x80008000u;                 // (-cx, -cy) packed
    const unsigned nczv = (ci.y & 0x0000FFFFu) ^ 0x00008000u; // (-cz, +0) packed
    const float rho_i = __high2float(*(__half2*)&ci.y);

    // scalar exclusion window: i is wave-uniform -> SGPR; t covers 128 j's
    const int s_i = __builtin_amdgcn_readfirstlane(i);
    const int tlo = ((s_i - 2 > 0) ? (s_i - 2) : 0) >> 7;
    const int thi = ((s_i + 2 < LRES - 1) ? (s_i + 2) : (LRES - 1)) >> 7;

    const unsigned lane2 = (unsigned)lane << 1;
    const unsigned exbits = __float_as_uint(1.0e9f);          // > any threshold

    // ---- pass 1: distances from LDS (lane owns 32 j's) + per-wave histogram ----
    const uint4* __restrict__ P4 = (const uint4*)Pl;
    unsigned d2u[32];
#pragma unroll
    for (int t = 0; t < 16; ++t) {
        uint4 u = P4[(t << 6) + lane];               // ds_read_b128, conflict-free
        int j0 = (t << 7) + (int)lane2;
        unsigned dxyA = hadd2u(u.x, ncxy);
        unsigned dzA  = hadd2u(u.y, nczv) & 0x0000FFFFu;
        float d2a = fdot2u(dxyA, dxyA, fdot2u(dzA, dzA, 0.0f));
        unsigned dxyB = hadd2u(u.z, ncxy);
        unsigned dzB  = hadd2u(u.w, nczv) & 0x0000FFFFu;
        float d2b = fdot2u(dxyB, dxyB, fdot2u(dzB, dzB, 0.0f));
        unsigned dua = __float_as_uint(d2a);
        unsigned dub = __float_as_uint(d2b);
        if (t == tlo || t == thi) {                  // wave-uniform branch
            int e0 = j0 - i;     e0 = (e0 < 0) ? -e0 : e0;
            int e1 = j0 + 1 - i; e1 = (e1 < 0) ? -e1 : e1;
            if (e0 <= 2) dua = exbits;
            if (e1 <= 2) dub = exbits;
        }
        d2u[2 * t]     = dua;
        d2u[2 * t + 1] = dub;
        if (dua <= 0x42C7FFFFu)                      // d2 < 100.0
            atomicAdd(&hist[w][(unsigned)(d2a * BINSCALE)], 1u);
        if (dub <= 0x42C7FFFFu)
            atomicAdd(&hist[w][(unsigned)(d2b * BINSCALE)], 1u);
    }
    LDS_FENCE();   // own wave's atomics visible (hist[w] is wave-private)

    // ---- scan: lane holds 2 bins; 64-lane inclusive scan; crossing lane sets T ----
    uint2 hv = *(const uint2*)&hist[w][lane << 1];
    unsigned p = hv.x + hv.y;
    unsigned s = p;
#pragma unroll
    for (int o = 1; o < 64; o <<= 1) {
        unsigned uu = __shfl_up(s, o, 64);
        if (lane >= o) s += uu;
    }
    unsigned e0s = s - p;
    if (s >= KSEL && e0s < KSEL) {
        unsigned sub = (e0s + hv.x >= KSEL) ? 0u : 1u;
        shT[w] = (lane << 1) + sub;                  // whole boundary bin selected
    }
    LDS_FENCE();
    const unsigned T   = shT[w];
    const unsigned tkb = __float_as_uint((float)(T + 1) * BINW);

    // ---- capture: branchless; store j (u16) only; d2 recomputed in eval ----
    unsigned cnt = 0;
#pragma unroll
    for (int m = 0; m < 32; ++m) {
        const unsigned jm = (unsigned)(((m >> 1) << 7) | (m & 1));
        unsigned short val = (unsigned short)(jm | lane2);
        unsigned sel  = (d2u[m] < tkb) ? 1u : 0u;
        unsigned widx = (cnt > NSLOT - 1) ? (NSLOT - 1) : cnt;
        slots[w][widx][lane] = val;
        cnt += sel;
    }
    LDS_FENCE();

    // ---- eval own slots (~1-4 iterations); d2 recomputed bit-identically ----
    float acc = 0.0f;
    for (unsigned k = 0; k < cnt; ++k) {
        unsigned j = slots[w][k][lane];
        uint2 pj = Pl[j];
        unsigned dxy = hadd2u(pj.x, ncxy);
        unsigned dz  = hadd2u(pj.y, nczv) & 0x0000FFFFu;
        float d2 = fdot2u(dxy, dxy, fdot2u(dz, dz, 0.0f));
        float r  = __fsqrt_rn(fmaxf(d2, 1e-12f));
        float rho_j = __high2float(*(__half2*)&pj.y);
        float x = (rho_i + rho_j - r) * (1.0f / 0.3f);
        float sp = fmaxf(x, 0.0f) + __logf(1.0f + __expf(-fabsf(x)));
        float t = fminf(fmaxf((r - 8.0f) * 0.5f, 0.0f), 1.0f);
        float sw = 1.0f - t * t * (3.0f - 2.0f * t);
        acc += 10.0f * sp * sw;
    }
#pragma unroll
    for (int o = 32; o > 0; o >>= 1) acc += __shfl_down(acc, o, 64);

    // ---- block combine -> ONE plain store per block ----
    if (lane == 0) shS[w] = acc;
    __syncthreads();
    if (tid == 0) {
        float v = 0.0f;
#pragma unroll
        for (int q = 0; q < 8; ++q) v += shS[q];
        partial[blockIdx.x] = v;
    }
}

// out[b] = sum of 256 per-block partials (blocks 256b .. 256b+255)
__global__ void reduce_kernel(const float* __restrict__ partial, float* __restrict__ out) {
    __shared__ float sh[4];
    const int b = blockIdx.x;
    const int tid = threadIdx.x;
    float acc = partial[(b << 8) + tid];
#pragma unroll
    for (int o = 32; o > 0; o >>= 1) acc += __shfl_down(acc, o, 64);
    if ((tid & 63) == 0) sh[tid >> 6] = acc;
    __syncthreads();
    if (tid == 0) out[b] = sh[0] + sh[1] + sh[2] + sh[3];
}

extern "C" void kernel_launch(void* const* d_in, const int* in_sizes, int n_in,
                              void* d_out, int out_size, void* d_ws, size_t ws_size,
                              hipStream_t stream) {
    const float* R    = (const float*)d_in[0];   // (8, 2048, 3) f32
    const int*   seq  = (const int*)d_in[1];     // (8, 2048) int
    const float* emb  = (const float*)d_in[2];   // (20, 16) f32
    const float* w    = (const float*)d_in[3];   // (1, 16) f32
    const float* bias = (const float*)d_in[4];   // (1,) f32
    float* out = (float*)d_out;                  // (8,) f32

    float* partial = (float*)d_ws;               // 8 KB (2048 block partials)

    repel_kernel<<<NB * LRES / 8, 512, 0, stream>>>(R, seq, emb, w, bias, partial);
    reduce_kernel<<<NB, 256, 0, stream>>>(partial, out);
}

// Round 7
// 83.338 us; speedup vs baseline: 1.0644x; 1.0165x over previous
//
#include <hip/hip_runtime.h>
#include <hip/hip_fp16.h>
#include <math.h>

#define LRES 2048
#define NB 8
#define KSEL 64
#define EMBD 16
#define NAA 20
#define NBIN 128
#define BINSCALE 1.28f          // bin = trunc(d2 * 1.28), d2 < 100 -> bin < 128
#define BINW 0.78125f           // 100/128, upper edge = (T+1)*BINW
#define NSLOT 16                // per-lane slot cap (Poisson(1) tail: P(>16) ~ 1e-14)

// packed-f16 dot product with f32 accumulate: d = a.x*b.x + a.y*b.y + c
static __device__ __forceinline__ float fdot2u(unsigned a, unsigned b, float c) {
#if __has_builtin(__builtin_amdgcn_fdot2)
    typedef _Float16 h2f __attribute__((ext_vector_type(2)));
    union { unsigned u; h2f h; } ua, ub;
    ua.u = a; ub.u = b;
    return __builtin_amdgcn_fdot2(ua.h, ub.h, c, false);
#else
    float d;
    asm("v_dot2_f32_f16 %0, %1, %2, %3" : "=v"(d) : "v"(a), "v"(b), "v"(c));
    return d;
#endif
}

static __device__ __forceinline__ unsigned hadd2u(unsigned a, unsigned b) {
    __half2 ha = *(__half2*)&a, hb = *(__half2*)&b;
    __half2 r = __hadd2(ha, hb);
    return *(unsigned*)&r;
}

// ---- DPP wave64 inclusive scan (VALU-only; replaces ds_bpermute shuffle chains) ----
// Sequence = LLVM AtomicOptimizer gfx9 wave64 scan:
//   row_shr:1/2/4/8 (all rows) + row_bcast:15 (rows 1,3) + row_bcast:31 (rows 2,3)
template <int CTRL, int RM>
static __device__ __forceinline__ unsigned dpp_u(unsigned v) {
    return (unsigned)__builtin_amdgcn_update_dpp(0, (int)v, CTRL, RM, 0xf, true);
}
static __device__ __forceinline__ unsigned wave_iscan_u(unsigned s) {
    s += dpp_u<0x111, 0xf>(s);   // row_shr:1
    s += dpp_u<0x112, 0xf>(s);   // row_shr:2
    s += dpp_u<0x114, 0xf>(s);   // row_shr:4
    s += dpp_u<0x118, 0xf>(s);   // row_shr:8
    s += dpp_u<0x142, 0xa>(s);   // row_bcast:15 -> rows 1,3
    s += dpp_u<0x143, 0xc>(s);   // row_bcast:31 -> rows 2,3
    return s;
}
static __device__ __forceinline__ float wave_iscan_f(float a) {
    a += __uint_as_float(dpp_u<0x111, 0xf>(__float_as_uint(a)));
    a += __uint_as_float(dpp_u<0x112, 0xf>(__float_as_uint(a)));
    a += __uint_as_float(dpp_u<0x114, 0xf>(__float_as_uint(a)));
    a += __uint_as_float(dpp_u<0x118, 0xf>(__float_as_uint(a)));
    a += __uint_as_float(dpp_u<0x142, 0xa>(__float_as_uint(a)));
    a += __uint_as_float(dpp_u<0x143, 0xc>(__float_as_uint(a)));
    return a;
}

#define LDS_FENCE() asm volatile("s_waitcnt lgkmcnt(0)" ::: "memory")

// ONE fused kernel: 512 threads = 8 waves = 8 rows per block; 256 blocks/batch.
// Block stages its batch's 2048 points (half4: x,y,z,rho) into LDS once
// (rho via 20-entry AA table), then each wave runs histogram-select-eval from LDS.
// Cross-lane scan/reduce are DPP (VALU) instead of ds_bpermute chains.
__global__ __launch_bounds__(512, 8) void repel_kernel(
    const float* __restrict__ R,
    const int* __restrict__ seq,
    const float* __restrict__ emb,
    const float* __restrict__ wv,
    const float* __restrict__ bias,
    float* __restrict__ partial)
{
    const int tid  = threadIdx.x;
    const int w    = tid >> 6;
    const int lane = tid & 63;
    const int row  = blockIdx.x * 8 + w;
    const int b    = row >> 11;
    const int i    = row & (LRES - 1);

    __shared__ uint2          Pl[LRES];             // 16 KB packed points
    __shared__ unsigned       hist[8][NBIN];        // 4 KB
    __shared__ unsigned short slots[8][NSLOT][64];  // 16 KB (j only)
    __shared__ float          rho_tab[NAA];         // 80 B
    __shared__ unsigned       shT[8];
    __shared__ float          shS[8];

    const float* __restrict__ Rb = R + b * (LRES * 3);
    const int*   __restrict__ Sb = seq + b * LRES;

    // ---- stage 0: rho table (20 dots of length 16) ----
    if (tid < NAA) {
        float x = bias[0];
#pragma unroll
        for (int d = 0; d < EMBD; ++d) x += emb[tid * EMBD + d] * wv[d];
        rho_tab[tid] = 1.6f + 1.2f / (1.0f + __expf(-x));
    }
    // zero own wave's histogram (2 bins/lane) + default T = NBIN-1
    *(uint2*)&hist[w][lane << 1] = make_uint2(0u, 0u);
    if (lane == 0) shT[w] = NBIN - 1;
    __syncthreads();

    // ---- stage 1: pack 4 points/thread into LDS ----
#pragma unroll
    for (int k = 0; k < 4; ++k) {
        int p = (k << 9) + tid;
        float x = Rb[p * 3 + 0], y = Rb[p * 3 + 1], z = Rb[p * 3 + 2];
        float rho = rho_tab[Sb[p]];
        __half2 h0 = __floats2half2_rn(x, y);
        __half2 h1 = __floats2half2_rn(z, rho);
        Pl[p] = make_uint2(*(unsigned*)&h0, *(unsigned*)&h1);
    }
    __syncthreads();

    // center: negated half2 (x,y) and masked+negated half2 (z, 0); rho_i as f32
    const uint2 ci = Pl[i];
    const unsigned ncxy = ci.x ^ 0x80008000u;                 // (-cx, -cy) packed
    const unsigned nczv = (ci.y & 0x0000FFFFu) ^ 0x00008000u; // (-cz, +0) packed
    const float rho_i = __high2float(*(__half2*)&ci.y);

    // scalar exclusion window: i is wave-uniform -> SGPR; t covers 128 j's
    const int s_i = __builtin_amdgcn_readfirstlane(i);
    const int tlo = ((s_i - 2 > 0) ? (s_i - 2) : 0) >> 7;
    const int thi = ((s_i + 2 < LRES - 1) ? (s_i + 2) : (LRES - 1)) >> 7;

    const unsigned lane2 = (unsigned)lane << 1;
    const unsigned exbits = __float_as_uint(1.0e9f);          // > any threshold

    // ---- pass 1: distances from LDS (lane owns 32 j's) + per-wave histogram ----
    const uint4* __restrict__ P4 = (const uint4*)Pl;
    unsigned d2u[32];
#pragma unroll
    for (int t = 0; t < 16; ++t) {
        uint4 u = P4[(t << 6) + lane];               // ds_read_b128, conflict-free
        int j0 = (t << 7) + (int)lane2;
        unsigned dxyA = hadd2u(u.x, ncxy);
        unsigned dzA  = hadd2u(u.y, nczv) & 0x0000FFFFu;
        float d2a = fdot2u(dxyA, dxyA, fdot2u(dzA, dzA, 0.0f));
        unsigned dxyB = hadd2u(u.z, ncxy);
        unsigned dzB  = hadd2u(u.w, nczv) & 0x0000FFFFu;
        float d2b = fdot2u(dxyB, dxyB, fdot2u(dzB, dzB, 0.0f));
        unsigned dua = __float_as_uint(d2a);
        unsigned dub = __float_as_uint(d2b);
        if (t == tlo || t == thi) {                  // wave-uniform branch
            int e0 = j0 - i;     e0 = (e0 < 0) ? -e0 : e0;
            int e1 = j0 + 1 - i; e1 = (e1 < 0) ? -e1 : e1;
            if (e0 <= 2) dua = exbits;
            if (e1 <= 2) dub = exbits;
        }
        d2u[2 * t]     = dua;
        d2u[2 * t + 1] = dub;
        if (dua <= 0x42C7FFFFu)                      // d2 < 100.0
            atomicAdd(&hist[w][(unsigned)(d2a * BINSCALE)], 1u);
        if (dub <= 0x42C7FFFFu)
            atomicAdd(&hist[w][(unsigned)(d2b * BINSCALE)], 1u);
    }
    LDS_FENCE();   // own wave's atomics visible (hist[w] is wave-private)

    // ---- scan: lane holds 2 bins; DPP wave64 inclusive scan; crossing lane sets T ----
    uint2 hv = *(const uint2*)&hist[w][lane << 1];
    unsigned p = hv.x + hv.y;
    unsigned s = wave_iscan_u(p);
    unsigned e0s = s - p;
    if (s >= KSEL && e0s < KSEL) {                   // unique crossing lane (if total >= 64)
        unsigned sub = (e0s + hv.x >= KSEL) ? 0u : 1u;
        shT[w] = (lane << 1) + sub;                  // whole boundary bin selected
    }
    LDS_FENCE();
    const unsigned T   = shT[w];
    const unsigned tkb = __float_as_uint((float)(T + 1) * BINW);

    // ---- capture: branchless; store j (u16) only; d2 recomputed in eval ----
    unsigned cnt = 0;
#pragma unroll
    for (int m = 0; m < 32; ++m) {
        const unsigned jm = (unsigned)(((m >> 1) << 7) | (m & 1));
        unsigned short val = (unsigned short)(jm | lane2);
        unsigned sel  = (d2u[m] < tkb) ? 1u : 0u;
        unsigned widx = (cnt > NSLOT - 1) ? (NSLOT - 1) : cnt;
        slots[w][widx][lane] = val;
        cnt += sel;
    }
    LDS_FENCE();

    // ---- eval own slots (~1-4 iterations); d2 recomputed bit-identically ----
    float acc = 0.0f;
    for (unsigned k = 0; k < cnt; ++k) {
        unsigned j = slots[w][k][lane];
        uint2 pj = Pl[j];
        unsigned dxy = hadd2u(pj.x, ncxy);
        unsigned dz  = hadd2u(pj.y, nczv) & 0x0000FFFFu;
        float d2 = fdot2u(dxy, dxy, fdot2u(dz, dz, 0.0f));
        float r  = __fsqrt_rn(fmaxf(d2, 1e-12f));
        float rho_j = __high2float(*(__half2*)&pj.y);
        float x = (rho_i + rho_j - r) * (1.0f / 0.3f);
        float sp = fmaxf(x, 0.0f) + __logf(1.0f + __expf(-fabsf(x)));
        float t = fminf(fmaxf((r - 8.0f) * 0.5f, 0.0f), 1.0f);
        float sw = 1.0f - t * t * (3.0f - 2.0f * t);
        acc += 10.0f * sp * sw;
    }

    // ---- DPP scan reduce (total lands in lane 63) -> block combine -> one store ----
    float atot = wave_iscan_f(acc);
    float wsum = __uint_as_float(__builtin_amdgcn_readlane(__float_as_uint(atot), 63));
    if (lane == 0) shS[w] = wsum;
    __syncthreads();
    if (tid == 0) {
        float v = 0.0f;
#pragma unroll
        for (int q = 0; q < 8; ++q) v += shS[q];
        partial[blockIdx.x] = v;
    }
}

// out[b] = sum of 256 per-block partials (blocks 256b .. 256b+255)
__global__ void reduce_kernel(const float* __restrict__ partial, float* __restrict__ out) {
    __shared__ float sh[4];
    const int b = blockIdx.x;
    const int tid = threadIdx.x;
    float acc = partial[(b << 8) + tid];
#pragma unroll
    for (int o = 32; o > 0; o >>= 1) acc += __shfl_down(acc, o, 64);
    if ((tid & 63) == 0) sh[tid >> 6] = acc;
    __syncthreads();
    if (tid == 0) out[b] = sh[0] + sh[1] + sh[2] + sh[3];
}

extern "C" void kernel_launch(void* const* d_in, const int* in_sizes, int n_in,
                              void* d_out, int out_size, void* d_ws, size_t ws_size,
                              hipStream_t stream) {
    const float* R    = (const float*)d_in[0];   // (8, 2048, 3) f32
    const int*   seq  = (const int*)d_in[1];     // (8, 2048) int
    const float* emb  = (const float*)d_in[2];   // (20, 16) f32
    const float* w    = (const float*)d_in[3];   // (1, 16) f32
    const float* bias = (const float*)d_in[4];   // (1,) f32
    float* out = (float*)d_out;                  // (8,) f32

    float* partial = (float*)d_ws;               // 8 KB (2048 block partials)

    repel_kernel<<<NB * LRES / 8, 512, 0, stream>>>(R, seq, emb, w, bias, partial);
    reduce_kernel<<<NB, 256, 0, stream>>>(partial, out);
}